// Round 1
// baseline (672.983 us; speedup 1.0000x reference)
//
#include <hip/hip_runtime.h>

typedef _Float16 f16x8 __attribute__((ext_vector_type(8)));
typedef float    f32x4 __attribute__((ext_vector_type(4)));

typedef const __attribute__((address_space(1))) void* gptr_t;
typedef __attribute__((address_space(3))) void* lptr_t;

__device__ __forceinline__ void gload_lds16(const void* g, void* l) {
  __builtin_amdgcn_global_load_lds((gptr_t)g, (lptr_t)l, 16, 0, 0);
}

constexpr int Bsz  = 8192;
constexpr int Nin  = 128;
constexpr int Hd   = 1024;
constexpr int Aact = 32;
constexpr int Od   = 64;
constexpr int KC = 384;           // OpenBLAS K-block (R10-validated)
constexpr float DELTA = 2e-5f;    // borderline window (R10-validated)
constexpr unsigned WCAP = 65536;

// k-permutation inside each 8-elem fragment: lets the A bit->f16 expansion be
// 12 VALU ops per fragment (u16-lane mask * 0x3C00). B digits are stored in
// the SAME permuted order, and every MFMA digit-accumulator is an exact sum
// (products are {0,1} x 11-bit-mantissa, K*|digit| fits <2^21 ULPs), so the
// permutation cannot change any result bit.
constexpr int KPERM[8] = {0, 2, 1, 3, 4, 6, 5, 7};

// ---- digit split + swizzle into MFMA B-fragment order (R13 layout + KPERM).
__global__ void wsplit_tiled_kernel(const float* __restrict__ src,  // [k][n] row-major
                                    _Float16* __restrict__ d1, _Float16* __restrict__ d2,
                                    _Float16* __restrict__ d3, int N, int K) {
  const int tid = threadIdx.x;
  const int j = tid >> 6, lane = tid & 63, l15 = lane & 15, quad = lane >> 4;
  const int n = blockIdx.x * 64 + j * 16 + l15;
  const int kb = blockIdx.y;
  const int k0 = kb * 32 + quad * 8;
  f16x8 o1, o2, o3;
#pragma unroll
  for (int e = 0; e < 8; ++e) {
    float w = src[(size_t)(k0 + KPERM[e]) * N + n];
    float m1 = rintf(w * 2048.0f);
    float q1 = m1 * (1.0f / 2048.0f);
    float r  = w - q1;                       // exact
    float m2 = rintf(r * 8388608.0f);        // 2^23
    float q2 = m2 * (1.0f / 8388608.0f);
    float r2 = r - q2;                       // exact
    float m3 = rintf(r2 * 34359738368.0f);   // 2^35
    o1[e] = (_Float16)q1;
    o2[e] = (_Float16)(m2 * (1.0f / 2048.0f));
    o3[e] = (_Float16)(m3 * (1.0f / 2048.0f));
  }
  size_t off = ((size_t)blockIdx.x * (K / 32) + kb) * 2048 + (j * 64 + lane) * 8;
  *(f16x8*)(d1 + off) = o1;
  *(f16x8*)(d2 + off) = o2;
  *(f16x8*)(d3 + off) = o3;
}

// ---- fp32 transpose: src[R][C] -> dst[C][R] (fixup column contiguity)
__global__ void transpose_f32_kernel(const float* __restrict__ src,
                                     float* __restrict__ dst, int R, int C) {
  __shared__ float tile[32][33];
  int c0 = blockIdx.x * 32, r0 = blockIdx.y * 32;
  for (int i = threadIdx.y; i < 32; i += 8)
    tile[i][threadIdx.x] = src[(size_t)(r0 + i) * C + c0 + threadIdx.x];
  __syncthreads();
  for (int i = threadIdx.y; i < 32; i += 8)
    dst[(size_t)(c0 + i) * R + r0 + threadIdx.x] = tile[threadIdx.x][i];
}

// ---- layer 1: EMULATE np's sgemm (K=128 single block, ascending fp32 FMA),
// then the fp32 trajectory; v resets to exact 0 -> pack 8 steps' spikes/byte.
__global__ __launch_bounds__(256)
void x1_kernel(const float* __restrict__ state, const float* __restrict__ w1,
               const float* __restrict__ b1, unsigned char* __restrict__ s1pack) {
  __shared__ float sA[64][129];
  __shared__ float sB[128][32];
  const int m0 = blockIdx.x * 64, n0 = blockIdx.y * 32;
  const int tid = threadIdx.x;
  for (int idx = tid; idx < 64 * 32; idx += 256) {
    int r = idx >> 5, c4 = (idx & 31) << 2;
    float4 v = *(const float4*)(state + (size_t)(m0 + r) * Nin + c4);
    sA[r][c4] = v.x; sA[r][c4 + 1] = v.y; sA[r][c4 + 2] = v.z; sA[r][c4 + 3] = v.w;
  }
  for (int idx = tid; idx < 128 * 8; idx += 256) {
    int r = idx >> 3, c4 = (idx & 7) << 2;
    *(float4*)&sB[r][c4] = *(const float4*)(w1 + (size_t)r * Hd + n0 + c4);
  }
  __syncthreads();
  const int tx = tid & 15, ty = tid >> 4;
  float acc[4][2] = {};
  for (int k = 0; k < 128; ++k) {           // ASCENDING, single acc: np order
    float a[4], b[2];
#pragma unroll
    for (int i = 0; i < 4; ++i) a[i] = sA[ty * 4 + i][k];
#pragma unroll
    for (int j = 0; j < 2; ++j) b[j] = sB[k][tx * 2 + j];
#pragma unroll
    for (int i = 0; i < 4; ++i)
#pragma unroll
      for (int j = 0; j < 2; ++j) acc[i][j] = __fmaf_rn(a[i], b[j], acc[i][j]);
  }
#pragma unroll
  for (int i = 0; i < 4; ++i)
#pragma unroll
    for (int j = 0; j < 2; ++j) {
      int m = m0 + ty * 4 + i, n = n0 + tx * 2 + j;
      float x = acc[i][j];
      float bb = b1[n];
      float v = 0.0f;
      unsigned bits = 0;
#pragma unroll
      for (int t = 0; t < 8; ++t) {
        float h = __fadd_rn(__fadd_rn(v, x), bb);   // np: (v1 + G1) + b1
        if (h >= 1.0f) { bits |= (1u << t); v = 0.0f; } else { v = h; }
      }
      s1pack[(size_t)m * Hd + n] = (unsigned char)bits;
    }
}

// ---- expand 8 spike bytes into 8 per-timestep f16 A-fragments, KPERM order.
// af[t] element e holds bit t of byte KPERM[e] as f16 0.0/1.0.
__device__ __forceinline__ void frag8_from_bits(unsigned d0, unsigned d1, f16x8* af) {
#pragma unroll
  for (int t = 0; t < 8; ++t) {
    union { unsigned u[4]; f16x8 v; } c;
    c.u[0] = ((d0 >> t) & 0x00010001u) * 0x3C00u;        // k0, k2
    c.u[1] = ((d0 >> (t + 8)) & 0x00010001u) * 0x3C00u;  // k1, k3
    c.u[2] = ((d1 >> t) & 0x00010001u) * 0x3C00u;        // k4, k6
    c.u[3] = ((d1 >> (t + 8)) & 0x00010001u) * 0x3C00u;  // k5, k7
    af[t] = c.v;
  }
}

// ---- GEMM2, ALL 8 timesteps batched: s1pack holds every step's spikes, and
// the v2 recurrence is elementwise-local -> run it in the epilogue over the 8
// register-resident G[t]. 48 MFMA per wave-k-step (3x gemm2d), B/A staged once
// instead of 8x, no v2 global round-trip. Borderline sites -> worklist; fixup
// replays the exact np trajectory and rewrites the whole 8-bit spike byte.
__global__ __launch_bounds__(256, 1)   // acc[2][3][8] = 192 VGPR -> 1 wave/EU
void gemm2all_kernel(const unsigned char* __restrict__ s1pack,
                     const _Float16* __restrict__ w2d1,
                     const _Float16* __restrict__ w2d2,
                     const _Float16* __restrict__ w2d3,
                     const float* __restrict__ b2,
                     unsigned char* __restrict__ s2p,
                     unsigned* __restrict__ wcnt, unsigned* __restrict__ wlist) {
  constexpr int K = Hd;
  __shared__ __align__(16) unsigned char lA[2][64 * 32];
  __shared__ __align__(16) _Float16 lB1[2][1024], lB2[2][1024], lB3[2][1024];
  const int tid = threadIdx.x;
  const int m0 = blockIdx.x * 64;
  const int n0 = blockIdx.y * 32;
  const int wave = tid >> 6, lane = tid & 63, l15 = lane & 15, quad = lane >> 4;
  // 32-col B tile = two 512-half j-subtiles inside wsplit's 64-col block
  const size_t bbase = (size_t)(blockIdx.y >> 1) * (K / 32) * 2048
                     + (size_t)(blockIdx.y & 1) * 1024;
  f32x4 acc[2][3][8] = {};

  auto stage = [&](int kb, int buf) {
    size_t bo = bbase + (size_t)kb * 2048;
    if (tid < 128) {                        // d1 + d3: lane x 16B linear dests
      gload_lds16(w2d1 + bo + tid * 8, &lB1[buf][tid * 8]);
      gload_lds16(w2d3 + bo + tid * 8, &lB3[buf][tid * 8]);
    } else {                                // d2 + A
      int s = tid - 128;
      gload_lds16(w2d2 + bo + s * 8, &lB2[buf][s * 8]);
      gload_lds16(s1pack + (size_t)(m0 + (s >> 1)) * Hd + kb * 32 + (s & 1) * 16,
                  &lA[buf][s * 16]);        // (s>>1)*32 + (s&1)*16 == s*16: linear
    }
  };
  stage(0, 0);
  for (int kb = 0; kb < K / 32; ++kb) {
    const int cur = kb & 1;
    __syncthreads();                        // drains vmcnt: buf[cur] staged
    if (kb + 1 < K / 32) stage(kb + 1, cur ^ 1);  // latency hides under MFMA
    unsigned d0, d1;
    {
      const unsigned* ap = (const unsigned*)&lA[cur][(wave * 16 + l15) * 32 + quad * 8];
      d0 = ap[0]; d1 = ap[1];
    }
    f16x8 af[8];
    frag8_from_bits(d0, d1, af);
    f16x8 bf[2][3];
#pragma unroll
    for (int j = 0; j < 2; ++j) {
      int off = j * 512 + lane * 8;         // fragment order: conflict-free
      bf[j][0] = *(const f16x8*)&lB1[cur][off];
      bf[j][1] = *(const f16x8*)&lB2[cur][off];
      bf[j][2] = *(const f16x8*)&lB3[cur][off];
    }
#pragma unroll
    for (int j = 0; j < 2; ++j)
#pragma unroll
      for (int d = 0; d < 3; ++d)
#pragma unroll
        for (int t = 0; t < 8; ++t)
          acc[j][d][t] = __builtin_amdgcn_mfma_f32_16x16x32_f16(af[t], bf[j][d],
                                                                acc[j][d][t], 0, 0, 0);
  }
  // epilogue: exact digit combine + full 8-step v2 recurrence in registers
#pragma unroll
  for (int j = 0; j < 2; ++j) {
    int n = n0 + j * 16 + l15;
    float bb = b2[n];
#pragma unroll
    for (int r = 0; r < 4; ++r) {
      int m = m0 + wave * 16 + quad * 4 + r;
      size_t idx = (size_t)m * Hd + n;
      float v = 0.0f;
      unsigned bits = 0;
#pragma unroll
      for (int t = 0; t < 8; ++t) {
        double ge = (double)acc[j][0][t][r]
                  + (double)acc[j][1][t][r] * (1.0 / 4096.0)
                  + (double)acc[j][2][t][r] * (1.0 / 16777216.0);
        float G = (float)ge;                       // cr-fp32 of exact gemm
        float h = __fadd_rn(__fadd_rn(v, G), bb);  // np: (v2 + G) + b2
        if (__builtin_expect(__builtin_fabsf(h - 1.0f) < DELTA, 0)) {
          unsigned pos = atomicAdd(wcnt, 1u);      // first-divergence flag: the
          if (pos < WCAP) wlist[pos] = (unsigned)idx;  // fixup rewrites ALL 8 bits
        }
        bool sp = (h >= 1.0f);
        if (sp) bits |= (1u << t);
        v = sp ? 0.0f : h;
      }
      s2p[idx] = (unsigned char)bits;
    }
  }
}

// ---- fixup: replay np's v2 recursion for worklist sites (3 lanes/site, one
// per KC block; branchless ascending adds; np fold (S1+S2)+S3) — R11-validated.
// Now writes the FULL 8-bit spike byte (trajectory after a borderline flip is
// rewritten wholesale), single launch, no v2 array.
__global__ __launch_bounds__(256)
void fixup_kernel(const unsigned* __restrict__ wcnt, const unsigned* __restrict__ wlist,
                  const unsigned char* __restrict__ s1pack, const float* __restrict__ w2tf,
                  const float* __restrict__ b2, unsigned char* __restrict__ s2p) {
  unsigned cnt = *wcnt;
  if (cnt > WCAP) cnt = WCAP;
  const int tid = threadIdx.x;
  const int lane = tid & 63;
  const int sl = lane / 3, blk3 = lane - sl * 3;
  const int wid = blockIdx.x * (blockDim.x >> 6) + (tid >> 6);
  const int nwaves = gridDim.x * (blockDim.x >> 6);
  for (unsigned base = (unsigned)wid * 21u; base < cnt; base += (unsigned)nwaves * 21u) {
    unsigned site = base + (unsigned)sl;
    bool act = (sl < 21) && (site < cnt);
    unsigned idx = act ? wlist[site] : 0u;
    int m = (int)(idx >> 10), n = (int)(idx & 1023u);
    const unsigned char* prow = s1pack + ((size_t)m << 10);
    const float* col = w2tf + ((size_t)n << 10);
    int kb = blk3 * KC;
    int kend = (blk3 == 2) ? Hd : kb + KC;
    float S[8] = {};
    if (act) {
      for (int k = kb; k < kend; k += 8) {
        float4 wa = *(const float4*)(col + k);
        float4 wb = *(const float4*)(col + k + 4);
        unsigned b0 = *(const unsigned*)(prow + k);
        unsigned b1 = *(const unsigned*)(prow + k + 4);
#pragma unroll
        for (int tau = 0; tau < 8; ++tau) {
          S[tau] = __fadd_rn(S[tau], ((b0 >> tau) & 1)        ? wa.x : 0.0f);
          S[tau] = __fadd_rn(S[tau], ((b0 >> (8 + tau)) & 1)  ? wa.y : 0.0f);
          S[tau] = __fadd_rn(S[tau], ((b0 >> (16 + tau)) & 1) ? wa.z : 0.0f);
          S[tau] = __fadd_rn(S[tau], ((b0 >> (24 + tau)) & 1) ? wa.w : 0.0f);
          S[tau] = __fadd_rn(S[tau], ((b1 >> tau) & 1)        ? wb.x : 0.0f);
          S[tau] = __fadd_rn(S[tau], ((b1 >> (8 + tau)) & 1)  ? wb.y : 0.0f);
          S[tau] = __fadd_rn(S[tau], ((b1 >> (16 + tau)) & 1) ? wb.z : 0.0f);
          S[tau] = __fadd_rn(S[tau], ((b1 >> (24 + tau)) & 1) ? wb.w : 0.0f);
        }
      }
    }
    float G[8];
#pragma unroll
    for (int tau = 0; tau < 8; ++tau) {
      float sB = __shfl(S[tau], lane + 1);
      float sC = __shfl(S[tau], lane + 2);
      G[tau] = __fadd_rn(__fadd_rn(S[tau], sB), sC);
    }
    if (act && blk3 == 0) {
      float bb = b2[n];
      float v = 0.0f;
      unsigned bits = 0;
      for (int tau = 0; tau < 8; ++tau) {
        float h = __fadd_rn(__fadd_rn(v, G[tau]), bb);
        bool sp = (h >= 1.0f);
        if (sp) bits |= (1u << tau);
        v = sp ? 0.0f : h;
      }
      s2p[idx] = (unsigned char)bits;
    }
  }
}

// ---- GEMM3, all 8 steps batched from packed s2 bits, LIF v3 recurrence fused
// into the epilogue (g3 buffer + v3rec kernel eliminated). Block 64x16, 4
// waves vertical; acc[3][8] = 96 VGPR -> 2 waves/EU.
__global__ __launch_bounds__(256, 2)
void gemm3all_kernel(const unsigned char* __restrict__ s2p,
                     const _Float16* __restrict__ w3d1, const _Float16* __restrict__ w3d2,
                     const _Float16* __restrict__ w3d3,
                     const float* __restrict__ b3, float* __restrict__ v3) {
  constexpr int K = Hd;
  __shared__ __align__(16) unsigned char lA[2][64 * 32];
  __shared__ __align__(16) _Float16 lB1[2][512], lB2[2][512], lB3[2][512];
  const int tid = threadIdx.x;
  const int m0 = blockIdx.x * 64;
  const int n0 = blockIdx.y * 16;           // j-subtile index = blockIdx.y
  const int wave = tid >> 6, lane = tid & 63, l15 = lane & 15, quad = lane >> 4;
  f32x4 acc[3][8] = {};
  auto stage = [&](int kb, int buf) {
    size_t bo = (size_t)kb * 2048 + (size_t)blockIdx.y * 512;
    if (tid < 64)       gload_lds16(w3d1 + bo + tid * 8, &lB1[buf][tid * 8]);
    else if (tid < 128) gload_lds16(w3d2 + bo + (tid - 64) * 8, &lB2[buf][(tid - 64) * 8]);
    else if (tid < 192) gload_lds16(w3d3 + bo + (tid - 128) * 8, &lB3[buf][(tid - 128) * 8]);
    if (tid >= 128) {
      int s = tid - 128;
      gload_lds16(s2p + (size_t)(m0 + (s >> 1)) * Hd + kb * 32 + (s & 1) * 16,
                  &lA[buf][s * 16]);
    }
  };
  stage(0, 0);
  for (int kb = 0; kb < K / 32; ++kb) {
    const int cur = kb & 1;
    __syncthreads();
    if (kb + 1 < K / 32) stage(kb + 1, cur ^ 1);
    unsigned d0, d1;
    {
      const unsigned* ap = (const unsigned*)&lA[cur][(wave * 16 + l15) * 32 + quad * 8];
      d0 = ap[0]; d1 = ap[1];
    }
    f16x8 af[8];
    frag8_from_bits(d0, d1, af);
    f16x8 bf[3];
    {
      int off = lane * 8;
      bf[0] = *(const f16x8*)&lB1[cur][off];
      bf[1] = *(const f16x8*)&lB2[cur][off];
      bf[2] = *(const f16x8*)&lB3[cur][off];
    }
#pragma unroll
    for (int d = 0; d < 3; ++d)
#pragma unroll
      for (int t = 0; t < 8; ++t)
        acc[d][t] = __builtin_amdgcn_mfma_f32_16x16x32_f16(af[t], bf[d], acc[d][t], 0, 0, 0);
  }
  int n = n0 + l15;
  float bb = b3[n];
#pragma unroll
  for (int r = 0; r < 4; ++r) {
    int m = m0 + wave * 16 + quad * 4 + r;
    float v = 0.0f;
#pragma unroll
    for (int t = 0; t < 8; ++t) {
      double ge = (double)acc[0][t][r]
                + (double)acc[1][t][r] * (1.0 / 4096.0)
                + (double)acc[2][t][r] * (1.0 / 16777216.0);
      float x3 = __fadd_rn((float)ge, bb);    // same op order as v3rec
      float dd = __fsub_rn(x3, v);
      v = __fadd_rn(v, __fmul_rn(dd, 0.5f));
    }
    v3[(size_t)m * Od + n] = v;
  }
}

// ---- final: fp32 op sequence as numpy; tanh clamped at |z| >= 7.90531111
// (R8-validated: np's tanh is exactly +/-1 on all live band coords)
__global__ void final_kernel(const float* __restrict__ v3, const float* __restrict__ eps,
                             float* __restrict__ action, float* __restrict__ logp) {
  int tid = threadIdx.x;
  int row = blockIdx.x * 8 + (tid >> 5);
  int j = tid & 31;
  float mu = v3[(size_t)row * Od + j];
  float ls = v3[(size_t)row * Od + 32 + j];
  ls = fminf(fmaxf(ls, -20.0f), 2.0f);
  float sd = (float)exp((double)ls);
  float e  = eps[(size_t)row * Aact + j];
  float z  = __fadd_rn(mu, __fmul_rn(sd, e));
  float a;
  if (__builtin_fabsf(z) >= 7.90531111f) a = __builtin_copysignf(1.0f, z);
  else                                   a = (float)tanh((double)z);
  float aa = __fmul_rn(a, a);
  float u  = __fadd_rn(__fsub_rn(1.0f, aa), 1e-7f);
  float lg = (float)log((double)u);
  float l  = __fmul_rn(__fmul_rn(-0.5f, e), e);
  l = __fsub_rn(l, ls);
  l = __fsub_rn(l, 0.9189385332046727f);
  float term = __fsub_rn(l, lg);
  action[(size_t)row * Aact + j] = a;
  double lp = (double)term;
#pragma unroll
  for (int w = 16; w >= 1; w >>= 1) lp += __shfl_xor(lp, w);
  if (j == 0) logp[row] = (float)lp;
}

extern "C" void kernel_launch(void* const* d_in, const int* in_sizes, int n_in,
                              void* d_out, int out_size, void* d_ws, size_t ws_size,
                              hipStream_t stream) {
  const float* state = (const float*)d_in[0];
  const float* w1 = (const float*)d_in[1];
  const float* b1 = (const float*)d_in[2];
  const float* w2 = (const float*)d_in[3];
  const float* b2 = (const float*)d_in[4];
  const float* w3 = (const float*)d_in[5];
  const float* b3 = (const float*)d_in[6];
  const float* eps = (const float*)d_in[7];
  float* out_action = (float*)d_out;
  float* out_logp = out_action + (size_t)Bsz * Aact;

  char* p = (char*)d_ws;
  auto take = [&](size_t bytes) {
    char* r = p;
    p += (bytes + 255) & ~(size_t)255;
    return r;
  };
  float* v3f = (float*)take((size_t)Bsz * Od * 4);                 // 2 MB
  unsigned char* s1pack = (unsigned char*)take((size_t)Bsz * Hd);  // 8 MB
  unsigned char* s2p = (unsigned char*)take((size_t)Bsz * Hd);     // 8 MB (bit-packed)
  _Float16* w2p1 = (_Float16*)take((size_t)Hd * Hd * 2);
  _Float16* w2p2 = (_Float16*)take((size_t)Hd * Hd * 2);
  _Float16* w2p3 = (_Float16*)take((size_t)Hd * Hd * 2);
  _Float16* w3p1 = (_Float16*)take((size_t)Od * Hd * 2);
  _Float16* w3p2 = (_Float16*)take((size_t)Od * Hd * 2);
  _Float16* w3p3 = (_Float16*)take((size_t)Od * Hd * 2);
  float* w2tf = (float*)take((size_t)Hd * Hd * 4);                 // 4 MB
  unsigned* wcnt = (unsigned*)take(8 * 4);
  unsigned* wlist = (unsigned*)take((size_t)WCAP * 4);             // 256 KB

  wsplit_tiled_kernel<<<dim3(Hd / 64, Hd / 32), 256, 0, stream>>>(w2, w2p1, w2p2, w2p3, Hd, Hd);
  wsplit_tiled_kernel<<<dim3(Od / 64, Hd / 32), 256, 0, stream>>>(w3, w3p1, w3p2, w3p3, Od, Hd);
  transpose_f32_kernel<<<dim3(Hd / 32, Hd / 32), dim3(32, 8), 0, stream>>>(w2, w2tf, Hd, Hd);
  x1_kernel<<<dim3(Bsz / 64, Hd / 32), 256, 0, stream>>>(state, w1, b1, s1pack);
  hipMemsetAsync(wcnt, 0, 8 * 4, stream);

  gemm2all_kernel<<<dim3(Bsz / 64, Hd / 32), 256, 0, stream>>>(s1pack, w2p1, w2p2, w2p3,
                                                               b2, s2p, wcnt, wlist);
  fixup_kernel<<<64, 256, 0, stream>>>(wcnt, wlist, s1pack, w2tf, b2, s2p);

  gemm3all_kernel<<<dim3(Bsz / 64, Od / 16), 256, 0, stream>>>(s2p, w3p1, w3p2, w3p3, b3, v3f);
  final_kernel<<<Bsz / 8, 256, 0, stream>>>(v3f, eps, out_action, out_logp);
}